// Round 13
// baseline (645.201 us; speedup 1.0000x reference)
//
#include <hip/hip_runtime.h>

#define H 64
#define NE 1500000
#define NLOC 20000
#define NEXP 200000
#define NL 400000
#define PAD_E 32
#define PAD_L 128
#define EPT 8
#define FILL_CHUNK 2048
#define NCHUNK ((NE + FILL_CHUNK - 1) / FILL_CHUNK)   // 733
#define FILL_BLOCKS (NCHUNK * 8)                      // 5864
#define DENSE1_BLOCKS 1280
#define PREP_BLOCKS (5 + DENSE1_BLOCKS + FILL_BLOCKS)
#define QFIN_BLOCKS 4096
#define LOC2_BLOCKS 1250

// ---- workspace layout (bytes) ---- (exactly the r1-proven 113,520,000)
// cnt_loc [0,80000)  cnt_exp [80000,880000)
// nbr_loc [880000,11120000)       nbr_exp(u16) [11120000,23920000)
// Ylh(f16)  [23920000,26480000)   Y2fh(f16)    [26480000,29040000)
// z_loc(f32)[29040000,34160000)   PH(f16)      [34160000,36720000)
// PQ/Qh(f16)[36720000,62320000)   T1h(f16)     [62320000,87920000)
// T2h(f16)  [87920000,113520000)
// fold scratch (66KB) lives at the head of d_out (overwritten by edge at the end)
#define WS_NEED 113520000ULL

typedef int vint4 __attribute__((ext_vector_type(4)));
typedef _Float16 f16x8 __attribute__((ext_vector_type(8)));
typedef float f32x4 __attribute__((ext_vector_type(4)));

__device__ __forceinline__ float bcastf(float v, int k) {
  return __int_as_float(__builtin_amdgcn_readlane(__float_as_int(v), k));
}
__device__ __forceinline__ int bcasti(int v, int k) {
  return __builtin_amdgcn_readlane(v, k);
}

// ONE launch: fold (blocks 0-4, -> d_out scratch) + dense1 + fill.
__global__ __launch_bounds__(256, 4) void prep_kernel(
    const int* __restrict__ src, const int* __restrict__ dst,
    int* __restrict__ cnt_loc, int* __restrict__ cnt_exp,
    int* __restrict__ nbr_loc, unsigned short* __restrict__ nbr_exp,
    const float* __restrict__ W2r_of, const float* __restrict__ W2l_of,
    const float* __restrict__ W2l_rev, const float* __restrict__ W2r_rev,
    const float* __restrict__ dW1, const float* __restrict__ b2_of,
    const float* __restrict__ b2_rev, float* __restrict__ fold,
    const float* __restrict__ emb_loc, _Float16* __restrict__ Ylh,
    const float* __restrict__ W1l_of)
{
  const int lane = threadIdx.x & 63;
  if (blockIdx.x < 5) {
    // fold: layer-2 weights through decoder (valid: no relu on layer 2)
    // fold[0]=Wf_q fold[4096]=Wf_y2 fold[8192]=Wf_t2 fold[12288]=Wf_p
    // fold[16384]=bf_q fold[16448]=bf_p
    const int w = threadIdx.x >> 6;
    const float* dW1a = dW1;
    const float* dW1b = dW1 + H * H;
    if (blockIdx.x < 4) {
      const float* A; const float* B; float* C;
      switch (blockIdx.x) {
        case 0:  A = W2r_of;  B = dW1b; C = fold;         break;
        case 1:  A = W2l_of;  B = dW1b; C = fold + 4096;  break;
        case 2:  A = W2l_rev; B = dW1a; C = fold + 8192;  break;
        default: A = W2r_rev; B = dW1a; C = fold + 12288; break;
      }
      float b[H];
#pragma unroll
      for (int k = 0; k < H; k++) b[k] = B[k * H + lane];
      for (int r = w * 16; r < w * 16 + 16; r++) {
        const float xv = A[r * H + lane];
        float a0 = 0.f, a1 = 0.f;
#pragma unroll
        for (int k = 0; k < H; k += 2) {
          a0 += bcastf(xv, k)     * b[k];
          a1 += bcastf(xv, k + 1) * b[k + 1];
        }
        C[r * H + lane] = a0 + a1;
      }
    } else if (w < 2) {
      const float* bv_src = (w == 0) ? b2_of : b2_rev;
      const float* B      = (w == 0) ? dW1b  : dW1a;
      float* o            = (w == 0) ? fold + 16384 : fold + 16448;
      float wk[H];
#pragma unroll
      for (int k = 0; k < H; k++) wk[k] = B[k * H + lane];
      const float bv = bv_src[lane];
      float a = 0.f;
#pragma unroll
      for (int k = 0; k < H; k++) a += bcastf(bv, k) * wk[k];
      o[lane] = a;
    }
  } else if (blockIdx.x < 5 + DENSE1_BLOCKS) {
    // dense1: Ylh = emb_loc @ W1l_of (fp16 out)
    const int vb = blockIdx.x - 5;
    const int gw = (vb * 256 + threadIdx.x) >> 6;
    const int nw = (DENSE1_BLOCKS * 256) >> 6;
    float w[H];
#pragma unroll
    for (int k = 0; k < H; k++) w[k] = W1l_of[k * H + lane];
    for (int i = gw; i < NLOC; i += nw) {
      const float xv = emb_loc[i * H + lane];
      float a0 = 0.f, a1 = 0.f;
#pragma unroll
      for (int k = 0; k < H; k += 2) {
        a0 += bcastf(xv, k)     * w[k];
        a1 += bcastf(xv, k + 1) * w[k + 1];
      }
      Ylh[i * H + lane] = (_Float16)(a0 + a1);
    }
  } else {
    // fill (r8/r10-proven body): floor = 3M fabric atomics @ ~22G/s
    const int fb = blockIdx.x - (5 + DENSE1_BLOCKS);
    const int p = fb & 7;
    const int chunk = fb >> 3;
    const long base = (long)chunk * FILL_CHUNK + threadIdx.x * EPT;
    if (base >= NE) return;
    vint4 s0 = __builtin_nontemporal_load((const vint4*)(src + base));
    vint4 s1 = __builtin_nontemporal_load((const vint4*)(src + base + 4));
    vint4 d0 = __builtin_nontemporal_load((const vint4*)(dst + base));
    vint4 d1 = __builtin_nontemporal_load((const vint4*)(dst + base + 4));
    int ss[EPT] = {s0.x, s0.y, s0.z, s0.w, s1.x, s1.y, s1.z, s1.w};
    int dd[EPT] = {d0.x, d0.y, d0.z, d0.w, d1.x, d1.y, d1.z, d1.w};
    const int elo = p * (NEXP / 8), ehi = elo + NEXP / 8;
    const int llo = p * (NLOC / 8), lhi = llo + NLOC / 8;
#pragma unroll
    for (int k = 0; k < EPT; k++) {
      const int d = dd[k];
      if (d >= elo && d < ehi) {
        int pos = atomicAdd(&cnt_exp[d], 1);
        if (pos < PAD_E) nbr_exp[d * PAD_E + pos] = (unsigned short)ss[k];
      }
    }
#pragma unroll
    for (int k = 0; k < EPT; k++) {
      const int s = ss[k];
      if (s >= llo && s < lhi) {
        int pos = atomicAdd(&cnt_loc[s], 1);
        if (pos < PAD_L) nbr_loc[s * PAD_L + pos] = dd[k];
      }
    }
  }
}

// passA': the ONLY MFMA pass. Computes z_exph in registers, then routes it
// through padded LDS (Zs[16][65], 2-way max bank aliasing = free) back into
// A-layout and applies the folded Wf_q / Wf_t2 immediately — z_exph never
// touches global. Outputs: T1h = emb_exp@W1l_rev; partialQ = z@Wf_q;
// T2h = z@Wf_t2. (Old passB's MFMA stage is thereby deleted.)
__global__ __launch_bounds__(256, 3) void passA_kernel(
    const unsigned short* __restrict__ nbr, const int* __restrict__ cnt,
    const _Float16* __restrict__ y, const float* __restrict__ x,
    const float* __restrict__ W1r_of, const float* __restrict__ b1_of,
    const float* __restrict__ W1l_rev,
    const float* __restrict__ Wf_q, const float* __restrict__ Wf_t2,
    _Float16* __restrict__ T1h, _Float16* __restrict__ PQ,
    _Float16* __restrict__ T2h)
{
  const int w = threadIdx.x >> 6;
  const int lane = threadIdx.x & 63;
  const int q = lane >> 4;
  const int cidx = lane & 15;
  const int rb = blockIdx.x * 16;
  const int col = w * 16 + cidx;

  __shared__ float Gs[16 * H];
  __shared__ float Zs[16][H + 1];

  f16x8 bz0, bz1, bt0, bt1;
#pragma unroll
  for (int j = 0; j < 8; j++) {
    bz0[j] = (_Float16)W1r_of[(q * 8 + j) * H + col];
    bz1[j] = (_Float16)W1r_of[(32 + q * 8 + j) * H + col];
    bt0[j] = (_Float16)W1l_rev[(q * 8 + j) * H + col];
    bt1[j] = (_Float16)W1l_rev[(32 + q * 8 + j) * H + col];
  }

  // gather-mean of Ylh rows (r10-proven body): wave w fills Gs rows w*4..w*4+3
  for (int rr = 0; rr < 4; rr++) {
    const int i = rb + w * 4 + rr;
    const int c = cnt[i];
    const int cc = min(c, PAD_E);
    const unsigned short* nb = nbr + (long)i * PAD_E;
    float s0 = 0.f, s1 = 0.f, s2 = 0.f, s3 = 0.f;
    const int id = (lane < cc) ? (int)nb[lane] : 0;
    int k = 0;
    const int m4 = cc & ~3;
    for (; k < m4; k += 4) {
      const int i0 = bcasti(id, k), i1 = bcasti(id, k + 1),
                i2 = bcasti(id, k + 2), i3 = bcasti(id, k + 3);
      s0 += (float)y[(long)i0 * H + lane];
      s1 += (float)y[(long)i1 * H + lane];
      s2 += (float)y[(long)i2 * H + lane];
      s3 += (float)y[(long)i3 * H + lane];
    }
    for (; k < cc; k++) s0 += (float)y[(long)bcasti(id, k) * H + lane];
    Gs[(w * 4 + rr) * H + lane] =
        ((s0 + s1) + (s2 + s3)) / fmaxf((float)c, 1.0f);
  }

  // A-frags from emb_exp (f32 -> f16)
  const float* ar = x + (long)(rb + cidx) * H;
  f16x8 a0, a1;
#pragma unroll
  for (int j = 0; j < 8; j++) {
    a0[j] = (_Float16)ar[q * 8 + j];
    a1[j] = (_Float16)ar[32 + q * 8 + j];
  }
  f32x4 accz = {0.f, 0.f, 0.f, 0.f};
  accz = __builtin_amdgcn_mfma_f32_16x16x32_f16(a0, bz0, accz, 0, 0, 0);
  accz = __builtin_amdgcn_mfma_f32_16x16x32_f16(a1, bz1, accz, 0, 0, 0);
  f32x4 acct = {0.f, 0.f, 0.f, 0.f};
  acct = __builtin_amdgcn_mfma_f32_16x16x32_f16(a0, bt0, acct, 0, 0, 0);
  acct = __builtin_amdgcn_mfma_f32_16x16x32_f16(a1, bt1, acct, 0, 0, 0);

  const float bj = b1_of[col];
  __syncthreads();   // Gs ready
#pragma unroll
  for (int reg = 0; reg < 4; reg++) {
    const int r = q * 4 + reg;
    const float z = fmaxf(accz[reg] + Gs[r * H + col] + bj, 0.f);
    Zs[r][col] = z;
    T1h[(long)(rb + r) * H + col] = (_Float16)acct[reg];
  }

  // folded B-frags (from d_out scratch)
  f16x8 bq0, bq1, b20, b21;
#pragma unroll
  for (int j = 0; j < 8; j++) {
    bq0[j] = (_Float16)Wf_q[(q * 8 + j) * H + col];
    bq1[j] = (_Float16)Wf_q[(32 + q * 8 + j) * H + col];
    b20[j] = (_Float16)Wf_t2[(q * 8 + j) * H + col];
    b21[j] = (_Float16)Wf_t2[(32 + q * 8 + j) * H + col];
  }
  __syncthreads();   // Zs complete
  f16x8 az0, az1;
#pragma unroll
  for (int j = 0; j < 8; j++) {
    az0[j] = (_Float16)Zs[cidx][q * 8 + j];
    az1[j] = (_Float16)Zs[cidx][32 + q * 8 + j];
  }
  f32x4 accq = {0.f, 0.f, 0.f, 0.f};
  accq = __builtin_amdgcn_mfma_f32_16x16x32_f16(az0, bq0, accq, 0, 0, 0);
  accq = __builtin_amdgcn_mfma_f32_16x16x32_f16(az1, bq1, accq, 0, 0, 0);
  f32x4 acc2 = {0.f, 0.f, 0.f, 0.f};
  acc2 = __builtin_amdgcn_mfma_f32_16x16x32_f16(az0, b20, acc2, 0, 0, 0);
  acc2 = __builtin_amdgcn_mfma_f32_16x16x32_f16(az1, b21, acc2, 0, 0, 0);
#pragma unroll
  for (int reg = 0; reg < 4; reg++) {
    const int r = q * 4 + reg;
    PQ[(long)(rb + r) * H + col]  = (_Float16)accq[reg];
    T2h[(long)(rb + r) * H + col] = (_Float16)acc2[reg];
  }
}

// Loc L1, fused with folded layer-2 dense (r12-proven): z = relu(gather(T1h)
// + x@Wr + b) -> z_loc f32; Y2fh = z@Wf_y2 -> f16.
__global__ __launch_bounds__(256, 3) void loc_gather_fused_kernel(
    const int* __restrict__ nbr, const int* __restrict__ cnt,
    const _Float16* __restrict__ T, const float* __restrict__ x,
    float* __restrict__ zout, _Float16* __restrict__ y2out,
    const float* __restrict__ Wr, const float* __restrict__ bias,
    const float* __restrict__ Wfy2, int n)
{
  const int lane = threadIdx.x & 63;
  const int gw = (blockIdx.x * 256 + threadIdx.x) >> 6;
  const int nw = (gridDim.x * 256) >> 6;
  float wr[H], wy[H];
#pragma unroll
  for (int k = 0; k < H; k++) {
    wr[k] = Wr[k * H + lane];
    wy[k] = Wfy2[k * H + lane];
  }
  const float bj = bias[lane];
  for (int i = gw; i < n; i += nw) {
    const int c = cnt[i];
    const int cc = min(c, PAD_L);
    const int* nb = nbr + (long)i * PAD_L;
    float s0 = 0.f, s1 = 0.f, s2 = 0.f, s3 = 0.f;
    int e = 0;
    while (e < cc) {
      const int m = min(cc - e, 64);
      const int id = (lane < m) ? nb[e + lane] : 0;
      int k = 0;
      const int m4 = m & ~3;
      for (; k < m4; k += 4) {
        const int i0 = bcasti(id, k), i1 = bcasti(id, k + 1),
                  i2 = bcasti(id, k + 2), i3 = bcasti(id, k + 3);
        s0 += (float)T[(long)i0 * H + lane];
        s1 += (float)T[(long)i1 * H + lane];
        s2 += (float)T[(long)i2 * H + lane];
        s3 += (float)T[(long)i3 * H + lane];
      }
      for (; k < m; k++) s0 += (float)T[(long)bcasti(id, k) * H + lane];
      e += m;
    }
    const float agg = ((s0 + s1) + (s2 + s3)) / fmaxf((float)c, 1.0f);
    const float xv = x[i * H + lane];
    float a0 = 0.f, a1 = 0.f;
#pragma unroll
    for (int k = 0; k < H; k += 2) {
      a0 += bcastf(xv, k)     * wr[k];
      a1 += bcastf(xv, k + 1) * wr[k + 1];
    }
    const float z = fmaxf(agg + bj + a0 + a1, 0.0f);
    zout[i * H + lane] = z;
    float y0 = 0.f, y1 = 0.f;
#pragma unroll
    for (int k = 0; k < H; k += 2) {
      y0 += bcastf(z, k)     * wy[k];
      y1 += bcastf(z, k + 1) * wy[k + 1];
    }
    y2out[i * H + lane] = (_Float16)(y0 + y1);
  }
}

// Finalize dispatch: blocks [0,QFIN) do Qh = partialQ + gatherE(Y2fh) + bf_q
// (in-place over PQ; per-row read-before-write); blocks [QFIN,..) do loc2:
// PH = gatherL(T2h) + z_loc@Wf_p + bf_p. The two halves are independent.
__global__ __launch_bounds__(256, 4) void fin_kernel(
    const unsigned short* __restrict__ nbr_e, const int* __restrict__ cnt_e,
    const _Float16* __restrict__ Y2fh, _Float16* __restrict__ PQ,
    const float* __restrict__ bf_q,
    const int* __restrict__ nbr_l, const int* __restrict__ cnt_l,
    const _Float16* __restrict__ T2h, const float* __restrict__ z_loc,
    _Float16* __restrict__ PH, const float* __restrict__ Wf_p,
    const float* __restrict__ bf_p)
{
  const int lane = threadIdx.x & 63;
  if (blockIdx.x < QFIN_BLOCKS) {
    const int gw = (blockIdx.x * 256 + threadIdx.x) >> 6;
    const int nw = (QFIN_BLOCKS * 256) >> 6;
    const float bq = bf_q[lane];
    for (int i = gw; i < NEXP; i += nw) {
      const int c = cnt_e[i];
      const int cc = min(c, PAD_E);
      const unsigned short* nb = nbr_e + (long)i * PAD_E;
      float s0 = 0.f, s1 = 0.f, s2 = 0.f, s3 = 0.f;
      const int id = (lane < cc) ? (int)nb[lane] : 0;
      int k = 0;
      const int m4 = cc & ~3;
      for (; k < m4; k += 4) {
        const int i0 = bcasti(id, k), i1 = bcasti(id, k + 1),
                  i2 = bcasti(id, k + 2), i3 = bcasti(id, k + 3);
        s0 += (float)Y2fh[(long)i0 * H + lane];
        s1 += (float)Y2fh[(long)i1 * H + lane];
        s2 += (float)Y2fh[(long)i2 * H + lane];
        s3 += (float)Y2fh[(long)i3 * H + lane];
      }
      for (; k < cc; k++) s0 += (float)Y2fh[(long)bcasti(id, k) * H + lane];
      const float agg = ((s0 + s1) + (s2 + s3)) / fmaxf((float)c, 1.0f);
      PQ[(long)i * H + lane] =
          (_Float16)((float)PQ[(long)i * H + lane] + agg + bq);
    }
  } else {
    const int vb = blockIdx.x - QFIN_BLOCKS;
    const int gw = (vb * 256 + threadIdx.x) >> 6;
    const int nw = (LOC2_BLOCKS * 256) >> 6;
    float wr[H];
#pragma unroll
    for (int k = 0; k < H; k++) wr[k] = Wf_p[k * H + lane];
    const float bj = bf_p[lane];
    for (int i = gw; i < NLOC; i += nw) {
      const int c = cnt_l[i];
      const int cc = min(c, PAD_L);
      const int* nb = nbr_l + (long)i * PAD_L;
      float s0 = 0.f, s1 = 0.f, s2 = 0.f, s3 = 0.f;
      int e = 0;
      while (e < cc) {
        const int m = min(cc - e, 64);
        const int id = (lane < m) ? nb[e + lane] : 0;
        int k = 0;
        const int m4 = m & ~3;
        for (; k < m4; k += 4) {
          const int i0 = bcasti(id, k), i1 = bcasti(id, k + 1),
                    i2 = bcasti(id, k + 2), i3 = bcasti(id, k + 3);
          s0 += (float)T2h[(long)i0 * H + lane];
          s1 += (float)T2h[(long)i1 * H + lane];
          s2 += (float)T2h[(long)i2 * H + lane];
          s3 += (float)T2h[(long)i3 * H + lane];
        }
        for (; k < m; k++) s0 += (float)T2h[(long)bcasti(id, k) * H + lane];
        e += m;
      }
      const float agg = ((s0 + s1) + (s2 + s3)) / fmaxf((float)c, 1.0f);
      const float xv = z_loc[i * H + lane];
      float a0 = 0.f, a1 = 0.f;
#pragma unroll
      for (int k = 0; k < H; k += 2) {
        a0 += bcastf(xv, k)     * wr[k];
        a1 += bcastf(xv, k + 1) * wr[k + 1];
      }
      PH[i * H + lane] = (_Float16)(agg + bj + a0 + a1);
    }
  }
}

// out[e] = sum_j relu(P[r,j] + Q[c,j] + db1[j]) * dW2[j] + db2  (P,Q fp16)
__global__ __launch_bounds__(256, 4) void edge_kernel(
    const int* __restrict__ row, const int* __restrict__ col,
    const _Float16* __restrict__ P, const _Float16* __restrict__ Q,
    const float* __restrict__ db1, const float* __restrict__ dW2,
    const float* __restrict__ db2, float* __restrict__ out)
{
  const int lane = threadIdx.x & 63;
  const int gw = (blockIdx.x * 256 + threadIdx.x) >> 6;
  const int nw = (gridDim.x * 256) >> 6;
  const float bj = db1[lane];
  const float w2 = dW2[lane];
  const float b2 = db2[0];
  for (int e = gw * 4; e < NL; e += nw * 4) {
    const int n4 = min(NL - e, 4);
    float h[4];
#pragma unroll
    for (int k = 0; k < 4; k++) {
      if (k < n4) {
        const int r = row[e + k], c = col[e + k];
        const float p = (float)P[(long)r * H + lane];
        const float q = (float)Q[(long)c * H + lane];
        h[k] = fmaxf(p + q + bj, 0.0f) * w2;
      } else h[k] = 0.f;
    }
#pragma unroll
    for (int off = 1; off < 64; off <<= 1) {
#pragma unroll
      for (int k = 0; k < 4; k++) h[k] += __shfl_xor(h[k], off);
    }
    if (lane == 0) {
#pragma unroll
      for (int k = 0; k < 4; k++)
        if (k < n4) out[e + k] = h[k] + b2;
    }
  }
}

extern "C" void kernel_launch(void* const* d_in, const int* in_sizes, int n_in,
                              void* d_out, int out_size, void* d_ws, size_t ws_size,
                              hipStream_t stream) {
  const float* emb_loc = (const float*)d_in[0];
  const float* emb_exp = (const float*)d_in[1];
  const float* W1l_of  = (const float*)d_in[2];
  const float* b1_of   = (const float*)d_in[3];
  const float* W1r_of  = (const float*)d_in[4];
  const float* W1l_rev = (const float*)d_in[5];
  const float* b1_rev  = (const float*)d_in[6];
  const float* W1r_rev = (const float*)d_in[7];
  const float* W2l_of  = (const float*)d_in[8];
  const float* b2_of   = (const float*)d_in[9];
  const float* W2r_of  = (const float*)d_in[10];
  const float* W2l_rev = (const float*)d_in[11];
  const float* b2_rev  = (const float*)d_in[12];
  const float* W2r_rev = (const float*)d_in[13];
  const float* dW1     = (const float*)d_in[14];
  const float* db1     = (const float*)d_in[15];
  const float* dW2     = (const float*)d_in[16];
  const float* db2     = (const float*)d_in[17];
  const int*   edge_of = (const int*)d_in[18];
  const int*   eli     = (const int*)d_in[20];

  const int* src = edge_of;
  const int* dst = edge_of + NE;
  const int* row = eli;
  const int* col = eli + NL;

  if (ws_size < WS_NEED) return;

  char* ws = (char*)d_ws;
  int*            cnt_loc = (int*)(ws);
  int*            cnt_exp = (int*)(ws + 80000);
  int*            nbr_loc = (int*)(ws + 880000);
  unsigned short* nbr_exp = (unsigned short*)(ws + 11120000);
  _Float16*       Ylh     = (_Float16*)(ws + 23920000);
  _Float16*       Y2fh    = (_Float16*)(ws + 26480000);
  float*          z_loc   = (float*)(ws + 29040000);
  _Float16*       PH      = (_Float16*)(ws + 34160000);
  _Float16*       PQ      = (_Float16*)(ws + 36720000);   // partialQ -> Qh
  _Float16*       T1h     = (_Float16*)(ws + 62320000);
  _Float16*       T2h     = (_Float16*)(ws + 87920000);
  float*          out     = (float*)d_out;

  // fold scratch at the head of d_out (66KB; fully overwritten by edge later)
  float* fold  = (float*)d_out;
  float* Wf_q  = fold;
  float* Wf_y2 = fold + 4096;
  float* Wf_t2 = fold + 8192;
  float* Wf_p  = fold + 12288;
  float* bf_q  = fold + 16384;
  float* bf_p  = fold + 16448;

  (void)hipMemsetAsync(ws, 0, 880000, stream);
  // 1: fold + dense1 + fill
  prep_kernel<<<PREP_BLOCKS, 256, 0, stream>>>(
      src, dst, cnt_loc, cnt_exp, nbr_loc, nbr_exp,
      W2r_of, W2l_of, W2l_rev, W2r_rev, dW1, b2_of, b2_rev, fold,
      emb_loc, Ylh, W1l_of);

  // 2: passA': T1h, partialQ, T2h (z_exph stays on-chip)
  passA_kernel<<<NEXP / 16, 256, 0, stream>>>(nbr_exp, cnt_exp, Ylh, emb_exp,
      W1r_of, b1_of, W1l_rev, Wf_q, Wf_t2, T1h, PQ, T2h);

  // 3: loc L1 fused: z_loc + Y2fh
  loc_gather_fused_kernel<<<1250, 256, 0, stream>>>(nbr_loc, cnt_loc, T1h,
      emb_loc, z_loc, Y2fh, W1r_rev, b1_rev, Wf_y2, NLOC);

  // 4: finalize: Qh (exp) || PH (loc) in one dispatch
  fin_kernel<<<QFIN_BLOCKS + LOC2_BLOCKS, 256, 0, stream>>>(
      nbr_exp, cnt_exp, Y2fh, PQ, bf_q,
      nbr_loc, cnt_loc, T2h, z_loc, PH, Wf_p, bf_p);

  // 5: decoder edge pass
  edge_kernel<<<2048, 256, 0, stream>>>(row, col, PH, PQ,
                                        db1, dW2, db2, out);
}